// Round 4
// baseline (170.875 us; speedup 1.0000x reference)
//
#include <hip/hip_runtime.h>
#include <math.h>

#define B_ 2
#define L_ 2048
#define H_ 16
#define E_ 64
#define D_ 64
#define DM_ 512
#define DH_ 256

typedef __bf16 bf16_t;
typedef bf16_t bf16x8_t __attribute__((ext_vector_type(8)));
typedef float f32x4_t __attribute__((ext_vector_type(4)));

// pack two floats to bf16x2 (round-up-at-halfway; 2 add + 1 perm)
__device__ __forceinline__ unsigned bpack(float hi, float lo) {
    unsigned uh = __float_as_uint(hi) + 0x8000u;
    unsigned ul = __float_as_uint(lo) + 0x8000u;
    return __builtin_amdgcn_perm(uh, ul, 0x07060302u);
}

__device__ __forceinline__ bf16_t to_bf16(float f) {
    union { float f; unsigned u; } x; x.f = f;
    unsigned r = (x.u + 0x7fffu + ((x.u >> 16) & 1u)) >> 16;
    union { unsigned short s; bf16_t b; } y; y.s = (unsigned short)r;
    return y.b;
}

// ---------------- w1 [512 k][256 n] f32 -> w1t [256 n][512 k] bf16 ------------
__global__ __launch_bounds__(256) void transpose_w1_kernel(
        const float* __restrict__ w1, bf16_t* __restrict__ w1t) {
    const int n = blockIdx.x;
    const int t = threadIdx.x;
    #pragma unroll
    for (int u = 0; u < 2; ++u) {
        int k = t + u * 256;
        float v = w1[(size_t)k * DH_ + n];
        w1t[(size_t)n * DM_ + k] = to_bf16(v);
    }
}

// ---------------- MLP via MFMA, split-K: fused = relu(raw@w1+b1)@w2 + b2 -----
// 256 blocks x 512 threads (8 waves). wave = (k-half, n-quarter).
__global__ __launch_bounds__(512) void mlp_kernel(
        const float* __restrict__ raw, const bf16_t* __restrict__ w1t,
        const float* __restrict__ b1, const float* __restrict__ w2,
        const float* __restrict__ b2, float* __restrict__ fused) {
    __shared__ bf16_t Rs[16][520];
    __shared__ float pk[4][4][16][17];   // [nq][nt][m][ncol]
    __shared__ float part[4][16];
    const int t = threadIdx.x;
    const int m0 = blockIdx.x * 16;
    #pragma unroll
    for (int u = 0; u < 4; ++u) {
        int idx = t + u * 512;
        int row = idx >> 7;
        int k = (idx & 127) << 2;
        f32x4_t v = *(const f32x4_t*)&raw[(size_t)(m0 + row) * DM_ + k];
        uint2 p;
        p.x = bpack(v[1], v[0]);
        p.y = bpack(v[3], v[2]);
        *(uint2*)&Rs[row][k] = p;
    }
    __syncthreads();
    const int wave = t >> 6;
    const int lane = t & 63;
    const int lrow = lane & 15;
    const int lgrp = lane >> 4;
    const int nq   = wave & 3;
    const int kh   = wave >> 2;
    const int n0w  = nq * 64;
    const int k0   = kh * 256;

    f32x4_t acc[4];
    #pragma unroll
    for (int nt = 0; nt < 4; ++nt) acc[nt] = (f32x4_t){0.f, 0.f, 0.f, 0.f};

    const bf16_t* wbase = w1t + (size_t)(n0w + lrow) * DM_ + k0 + lgrp * 8;
    #pragma unroll
    for (int s = 0; s < 8; ++s) {
        bf16x8_t a = *(const bf16x8_t*)&Rs[lrow][k0 + s * 32 + lgrp * 8];
        #pragma unroll
        for (int nt = 0; nt < 4; ++nt) {
            bf16x8_t b = *(const bf16x8_t*)(wbase + nt * 16 * DM_ + s * 32);
            acc[nt] = __builtin_amdgcn_mfma_f32_16x16x32_bf16(a, b, acc[nt], 0, 0, 0);
        }
    }
    if (kh == 1) {
        #pragma unroll
        for (int nt = 0; nt < 4; ++nt)
            #pragma unroll
            for (int r = 0; r < 4; ++r)
                pk[nq][nt][lgrp * 4 + r][lrow] = acc[nt][r];
    }
    __syncthreads();
    if (kh == 0) {
        float rowpart[4] = {0.f, 0.f, 0.f, 0.f};
        #pragma unroll
        for (int nt = 0; nt < 4; ++nt) {
            int n = n0w + nt * 16 + lrow;
            float b1v = b1[n];
            float w2v = w2[n];
            #pragma unroll
            for (int r = 0; r < 4; ++r) {
                float h = acc[nt][r] + pk[nq][nt][lgrp * 4 + r][lrow] + b1v;
                h = h > 0.f ? h : 0.f;
                rowpart[r] += h * w2v;
            }
        }
        #pragma unroll
        for (int r = 0; r < 4; ++r) {
            float v = rowpart[r];
            v += __shfl_xor(v, 1);
            v += __shfl_xor(v, 2);
            v += __shfl_xor(v, 4);
            v += __shfl_xor(v, 8);
            if (lrow == 0) part[nq][lgrp * 4 + r] = v;
        }
    }
    __syncthreads();
    if (t < 16)
        fused[m0 + t] = part[0][t] + part[1][t] + part[2][t] + part[3][t] + b2[0];
}

// ---------------- flash attention, dbuf LDS, 1 barrier/tile -------------------
struct TileRegs { f32x4_t k[4]; float v[16]; float m; };

__global__ __launch_bounds__(256) void attn_kernel(
        const float* __restrict__ Q, const float* __restrict__ K,
        const float* __restrict__ V, const float* __restrict__ fused,
        const float* __restrict__ alpha_trend, float* __restrict__ out) {
    __shared__ bf16_t Ks[2][64][72];          // [s][e], 144-B rows (16-aligned)
    __shared__ bf16_t Vt[2][64][76];          // [d][s], 152-B rows (bank-spread)
    __shared__ unsigned short Ps[4][16][68];  // per-wave P scratch
    __shared__ float moms[2][64];

    const int bid  = blockIdx.x;
    const int bh   = bid & 31;
    const int qt   = 31 - (bid >> 5);         // heavy diagonals first
    const int h    = bh & 15;
    const int b    = bh >> 4;
    const int q0   = qt << 6;
    const int tid  = threadIdx.x;
    const int wave = tid >> 6;
    const int lane = tid & 63;
    const int lrow = lane & 15;
    const int lgrp = lane >> 4;

    const float c1      = 0.18033688f;        // 0.125 * log2(e)
    const float ascale2 = alpha_trend[h] * c1;
    const size_t bl     = (size_t)b * L_;
    const int qw0       = q0 + wave * 16;

    const float* Kb = K + (bl * H_ + h) * E_;
    const float* Vb = V + (bl * H_ + h) * D_;
    const float* fp = fused + bl;

    const int krow = tid >> 4;
    const int ke0  = (tid & 15) << 2;
    const int vd   = tid & 63;
    const int vsb  = tid >> 6;

    // Q fragments, prescaled by c1
    bf16x8_t a_lo, a_hi;
    {
        const float* qp = Q + ((bl + qw0 + lrow) * H_ + h) * E_ + lgrp * 8;
        f32x4_t v0 = *(const f32x4_t*)(qp);
        f32x4_t v1 = *(const f32x4_t*)(qp + 4);
        f32x4_t v2 = *(const f32x4_t*)(qp + 32);
        f32x4_t v3 = *(const f32x4_t*)(qp + 36);
        #pragma unroll
        for (int k = 0; k < 4; ++k) {
            a_lo[k]     = to_bf16(v0[k] * c1);
            a_lo[4 + k] = to_bf16(v1[k] * c1);
            a_hi[k]     = to_bf16(v2[k] * c1);
            a_hi[4 + k] = to_bf16(v3[k] * c1);
        }
    }
    float mq[4];
    #pragma unroll
    for (int r = 0; r < 4; ++r) {
        int l = qw0 + lgrp * 4 + r;
        mq[r] = (l == 0) ? 0.f : fp[l] - fp[l - 1];
    }

    f32x4_t Oacc[4];
    #pragma unroll
    for (int c = 0; c < 4; ++c) Oacc[c] = (f32x4_t){0.f, 0.f, 0.f, 0.f};
    float rowsum[4] = {0.f, 0.f, 0.f, 0.f};

    TileRegs tr;
    // ---- load tile st into tr ----
    #define LOAD_TILE(st_) do {                                                   \
        const int s0_ = (st_) << 6;                                               \
        _Pragma("unroll")                                                         \
        for (int u = 0; u < 4; ++u)                                               \
            tr.k[u] = *(const f32x4_t*)&Kb[(s0_ + krow + u * 16) * (H_ * E_) + ke0]; \
        _Pragma("unroll")                                                         \
        for (int j = 0; j < 16; ++j)                                              \
            tr.v[j] = Vb[(s0_ + vsb * 16 + j) * (H_ * D_) + vd];                  \
        if (tid < 64) {                                                           \
            int l_ = s0_ + tid;                                                   \
            tr.m = (l_ == 0) ? 0.f : fp[l_] - fp[l_ - 1];                         \
        }                                                                         \
    } while (0)

    // ---- stage tr into LDS buffer pb ----
    #define STAGE_TILE(pb_) do {                                                  \
        _Pragma("unroll")                                                         \
        for (int u = 0; u < 4; ++u) {                                             \
            uint2 p;                                                              \
            p.x = bpack(tr.k[u][1], tr.k[u][0]);                                  \
            p.y = bpack(tr.k[u][3], tr.k[u][2]);                                  \
            *(uint2*)&Ks[pb_][krow + u * 16][ke0] = p;                            \
        }                                                                         \
        _Pragma("unroll")                                                         \
        for (int u = 0; u < 4; ++u) {                                             \
            uint2 p;                                                              \
            p.x = bpack(tr.v[u * 4 + 1], tr.v[u * 4 + 0]);                        \
            p.y = bpack(tr.v[u * 4 + 3], tr.v[u * 4 + 2]);                        \
            *(uint2*)&Vt[pb_][vd][vsb * 16 + u * 4] = p;                          \
        }                                                                         \
        if (tid < 64) moms[pb_][tid] = tr.m;                                      \
    } while (0)

    // prologue
    LOAD_TILE(0);
    STAGE_TILE(0);
    if (qt >= 1) LOAD_TILE(1);
    __syncthreads();

    for (int st = 0; st <= qt; ++st) {
        const int cb = st & 1;
        if (st < qt) STAGE_TILE((st + 1) & 1);
        if (st + 2 <= qt) LOAD_TILE(st + 2);

        // S = Q K^T (log2 domain via prescale)
        f32x4_t Sacc[4];
        #pragma unroll
        for (int c = 0; c < 4; ++c) Sacc[c] = (f32x4_t){0.f, 0.f, 0.f, 0.f};
        #pragma unroll
        for (int c = 0; c < 4; ++c) {
            bf16x8_t b_lo = *(const bf16x8_t*)&Ks[cb][c * 16 + lrow][lgrp * 8];
            bf16x8_t b_hi = *(const bf16x8_t*)&Ks[cb][c * 16 + lrow][32 + lgrp * 8];
            Sacc[c] = __builtin_amdgcn_mfma_f32_16x16x32_bf16(a_lo, b_lo, Sacc[c], 0, 0, 0);
            Sacc[c] = __builtin_amdgcn_mfma_f32_16x16x32_bf16(a_hi, b_hi, Sacc[c], 0, 0, 0);
        }

        // P = exp2(S - ascale2*|dm|)
        float rowe[4][4];
        #pragma unroll
        for (int c = 0; c < 4; ++c) {
            float ms = moms[cb][c * 16 + lrow];
            #pragma unroll
            for (int r = 0; r < 4; ++r) {
                float arg = Sacc[c][r] - ascale2 * fabsf(mq[r] - ms);
                rowe[c][r] = __builtin_amdgcn_exp2f(arg);
            }
        }
        if (st == qt) {
            const int s0 = st << 6;
            #pragma unroll
            for (int c = 0; c < 4; ++c) {
                int sg = s0 + c * 16 + lrow;
                #pragma unroll
                for (int r = 0; r < 4; ++r)
                    if (sg > qw0 + lgrp * 4 + r) rowe[c][r] = 0.f;
            }
        }
        // P -> wave-private LDS (bf16) + row sums
        unsigned short* Psw = &Ps[wave][0][0];
        #pragma unroll
        for (int c = 0; c < 4; ++c) {
            #pragma unroll
            for (int r = 0; r < 4; ++r) {
                unsigned u = (__float_as_uint(rowe[c][r]) + 0x8000u) & 0xffff0000u;
                Psw[(lgrp * 4 + r) * 68 + c * 16 + lrow] = (unsigned short)(u >> 16);
                rowsum[r] += __uint_as_float(u);
            }
        }

        // O += P V
        #pragma unroll
        for (int hh = 0; hh < 2; ++hh) {
            union { uint2 u2[2]; bf16x8_t v; } ab;
            ab.u2[0] = *(const uint2*)&Psw[lrow * 68 + hh * 32 + lgrp * 8];
            ab.u2[1] = *(const uint2*)&Psw[lrow * 68 + hh * 32 + lgrp * 8 + 4];
            #pragma unroll
            for (int c2 = 0; c2 < 4; ++c2) {
                union { uint2 u2[2]; bf16x8_t v; } bb;
                bb.u2[0] = *(const uint2*)&Vt[cb][c2 * 16 + lrow][hh * 32 + lgrp * 8];
                bb.u2[1] = *(const uint2*)&Vt[cb][c2 * 16 + lrow][hh * 32 + lgrp * 8 + 4];
                Oacc[c2] = __builtin_amdgcn_mfma_f32_16x16x32_bf16(ab.v, bb.v, Oacc[c2], 0, 0, 0);
            }
        }
        __syncthreads();
    }

    // epilogue
    #pragma unroll
    for (int r = 0; r < 4; ++r) {
        float rs = rowsum[r];
        rs += __shfl_xor(rs, 1);
        rs += __shfl_xor(rs, 2);
        rs += __shfl_xor(rs, 4);
        rs += __shfl_xor(rs, 8);
        float inv = 1.f / rs;
        size_t orow = ((bl + qw0 + lgrp * 4 + r) * H_ + h) * D_;
        #pragma unroll
        for (int c = 0; c < 4; ++c)
            out[orow + c * 16 + lrow] = Oacc[c][r] * inv;
    }
    #undef LOAD_TILE
    #undef STAGE_TILE
}

extern "C" void kernel_launch(void* const* d_in, const int* in_sizes, int n_in,
                              void* d_out, int out_size, void* d_ws, size_t ws_size,
                              hipStream_t stream) {
    const float* Q     = (const float*)d_in[0];
    const float* K     = (const float*)d_in[1];
    const float* V     = (const float*)d_in[2];
    const float* raw   = (const float*)d_in[3];
    const float* w1    = (const float*)d_in[4];
    const float* b1    = (const float*)d_in[5];
    const float* w2    = (const float*)d_in[6];
    const float* b2    = (const float*)d_in[7];
    const float* alpha = (const float*)d_in[8];
    float* out = (float*)d_out;

    float* fused = (float*)d_ws;                    // B*L floats
    bf16_t* w1t  = (bf16_t*)(fused + B_ * L_);      // 256*512 bf16

    transpose_w1_kernel<<<DH_, 256, 0, stream>>>(w1, w1t);
    mlp_kernel<<<B_ * L_ / 16, 512, 0, stream>>>(raw, w1t, b1, w2, b2, fused);
    attn_kernel<<<B_ * H_ * (L_ / 64), 256, 0, stream>>>(Q, K, V, fused, alpha, out);
}